// Round 10
// baseline (270.060 us; speedup 1.0000x reference)
//
#include <hip/hip_runtime.h>
#include <hip/hip_bf16.h>
#include <stdint.h>

// SheafAttention on MI355X (gfx950).  B=4, T=2048, D=1024, H=16, S=64.
//
// Pipeline:
//  1. ptable: p-adic bias + causal mask -> 128 fragment tiles indexed by
//     e = (qtile-ktile)*4 + wave, in MFMA C-fragment lane order (512 KB, L2-resident).
//  2. absmax6   3. prep_w (quant + stalk-fold; Q pre-scaled 0.125*log2e)   4. xcvt
//  5. gemm128: QKV = xb @ W_all^T.  R15: K-loop unrolled x2 (two 64-slabs staged into
//     a double-width LDS buffer per barrier cycle -> one vmcnt drain per 128 of K,
//     halving drain count — the same transform that took attn 77->68us in R13/R14).
//  6. vtrans: V part of QKV -> Vt[bh][s][t]
//  7. attn (R14 structure, unchanged): 4 q-tiles/block {p,15-p,16+p,31-p} share each
//     kb/vb fragment read; two-phase per k-tile (K-frags then V-frags); bias C-init
//     from table; ones-MFMA row-sum; x2 stage unroll, one drain per 2 k-tiles.
//     OCCUPANCY AXIS CLOSED (R10-R12): natural footprint ~168 unified regs => 2
//     waves/SIMD; (256,4)/cap128 and (256,3) variants all spilled or lost sharing.
//     STAY (256,2). TRIPWIRE: attn WRITE_SIZE must stay ~16MB.
//  8. gemm128: out = O @ Wo^T (fp32), same x2-unrolled structure.

typedef __bf16 bf16_t;
typedef __attribute__((ext_vector_type(4))) __bf16 bf16x4;
typedef __attribute__((ext_vector_type(8))) __bf16 bf16x8;
typedef __attribute__((ext_vector_type(4))) float f32x4;

#define BB 4
#define TT 2048
#define DD 1024
#define HH 16
#define SS 64

__device__ __forceinline__ float quant6(float v, float s) {
    float q = rintf(v / s);
    q = fminf(fmaxf(q, -31.0f), 31.0f);
    return q * s;
}

__device__ __forceinline__ float fexp2(float x) {
#if __has_builtin(__builtin_amdgcn_exp2f)
    return __builtin_amdgcn_exp2f(x);
#else
    return exp2f(x);
#endif
}

typedef __attribute__((address_space(3))) uint32_t lds_u32;
typedef const __attribute__((address_space(1))) uint32_t glb_u32;

// ---------------------------------------------------------------- p-adic bias table
// tbl[((e*4 + c)*64 + lane)*4 + r], e = (qtile-ktile)*4 + wave.
// d = e*16 + (lane&15) - (c*16 + (lane>>4)*4 + r).
// d<0 -> -inf (causal), d==0 -> pb2*16, else pb2*ctz(d).
__global__ __launch_bounds__(256) void ptable_kernel(const float* __restrict__ psc,
                                                     float* __restrict__ tbl) {
    const int idx = blockIdx.x * 256 + threadIdx.x;   // (e*4 + c)*64 + lane, 32768 total
    const int l = idx & 63, c = (idx >> 6) & 3, e = idx >> 8;
    const int l15 = l & 15, quad = l >> 4;
    const float pb2 = psc[0] * 1.44269504089f * 0.0625f;
    f32x4 v;
    #pragma unroll
    for (int r = 0; r < 4; ++r) {
        const int d = e * 16 + l15 - (c * 16 + quad * 4 + r);
        float val;
        if (d < 0) val = -INFINITY;
        else if (d == 0) val = pb2 * 16.0f;
        else val = pb2 * (float)__builtin_ctz((unsigned)d);
        v[r] = val;
    }
    *(f32x4*)(tbl + (size_t)idx * 4) = v;
}

// ---------------------------------------------------------------- fused absmax (6 tensors)
__global__ __launch_bounds__(256) void absmax6(const float* __restrict__ wq,
                                               const float* __restrict__ wk,
                                               const float* __restrict__ wv,
                                               const float* __restrict__ wo,
                                               const float* __restrict__ wu,
                                               const float* __restrict__ wsv,
                                               float* __restrict__ amax) {
    const int t = blockIdx.y;
    const float* src = (t == 0) ? wq : (t == 1) ? wk : (t == 2) ? wv
                     : (t == 3) ? wo : (t == 4) ? wu : wsv;
    const int n4 = (t < 4) ? (1048576 / 4) : (4096 / 4);
    float m = 0.0f;
    for (int i = blockIdx.x * blockDim.x + threadIdx.x; i < n4; i += gridDim.x * blockDim.x) {
        float4 v = ((const float4*)src)[i];
        m = fmaxf(m, fmaxf(fmaxf(fabsf(v.x), fabsf(v.y)), fmaxf(fabsf(v.z), fabsf(v.w))));
    }
    #pragma unroll
    for (int mask = 32; mask > 0; mask >>= 1)
        m = fmaxf(m, __shfl_xor(m, mask));
    __shared__ float red[4];
    int w = threadIdx.x >> 6;
    if ((threadIdx.x & 63) == 0) red[w] = m;
    __syncthreads();
    if (threadIdx.x == 0) {
        m = fmaxf(fmaxf(red[0], red[1]), fmaxf(red[2], red[3]));
        atomicMax((int*)(amax + t), __float_as_int(m));
    }
}

// ---------------------------------------------------------------- x fp32 -> bf16
__global__ __launch_bounds__(256) void xcvt_kernel(const float* __restrict__ x,
                                                   bf16_t* __restrict__ xb) {
    int i = (blockIdx.x * 256 + threadIdx.x) * 8;
    float4 f0 = *(const float4*)(x + i);
    float4 f1 = *(const float4*)(x + i + 4);
    bf16x8 v;
    v[0] = (bf16_t)f0.x; v[1] = (bf16_t)f0.y; v[2] = (bf16_t)f0.z; v[3] = (bf16_t)f0.w;
    v[4] = (bf16_t)f1.x; v[5] = (bf16_t)f1.y; v[6] = (bf16_t)f1.z; v[7] = (bf16_t)f1.w;
    *(bf16x8*)(xb + i) = v;
}

// ---------------------------------------------------------------- weight prep (quant + fold)
__global__ __launch_bounds__(256) void prep_w(const float* __restrict__ wq,
                                              const float* __restrict__ wk,
                                              const float* __restrict__ wv,
                                              const float* __restrict__ wo,
                                              const float* __restrict__ wu,
                                              const float* __restrict__ wsv,
                                              const float* __restrict__ amax,
                                              bf16_t* __restrict__ W_all,
                                              bf16_t* __restrict__ Wo) {
    const int which = blockIdx.y;
    if (blockIdx.x < 512) {
        const float* src = which ? wo : wv;
        bf16_t* dst = which ? Wo : (W_all + (size_t)2048 * 1024);
        float s = amax[which ? 3 : 2] / 31.0f + 1e-8f;
        int i = (blockIdx.x * 256 + threadIdx.x) * 8;
        float4 f0 = *(const float4*)(src + i);
        float4 f1 = *(const float4*)(src + i + 4);
        bf16x8 v;
        v[0] = (bf16_t)quant6(f0.x, s); v[1] = (bf16_t)quant6(f0.y, s);
        v[2] = (bf16_t)quant6(f0.z, s); v[3] = (bf16_t)quant6(f0.w, s);
        v[4] = (bf16_t)quant6(f1.x, s); v[5] = (bf16_t)quant6(f1.y, s);
        v[6] = (bf16_t)quant6(f1.z, s); v[7] = (bf16_t)quant6(f1.w, s);
        *(bf16x8*)(dst + i) = v;
        return;
    }
    const int fx = blockIdx.x - 512;
    const float* wbig = which ? wk : wq;
    const float* wsml = which ? wsv : wu;
    const float sb = amax[which ? 1 : 0] / 31.0f + 1e-8f;
    const float ss = amax[which ? 5 : 4] / 31.0f + 1e-8f;
    const float oscale = which ? 1.0f : 0.125f * 1.44269504089f;
    bf16_t* outp = W_all + (size_t)which * 1024 * 1024;
    const int h = fx >> 4, n0 = (fx & 15) * 64;
    const int w = threadIdx.x >> 6, l = threadIdx.x & 63;
    const int l15 = l & 15, quad = l >> 4, q8 = quad * 8;
    const int m0 = w * 16;

    bf16x8 af[2];
    #pragma unroll
    for (int kc = 0; kc < 2; ++kc) {
        const float* src = wsml + (m0 + l15) * 64 + kc * 32 + q8;
        float4 f0 = *(const float4*)(src);
        float4 f1 = *(const float4*)(src + 4);
        bf16x8 a;
        a[0] = (bf16_t)quant6(f0.x, ss); a[1] = (bf16_t)quant6(f0.y, ss);
        a[2] = (bf16_t)quant6(f0.z, ss); a[3] = (bf16_t)quant6(f0.w, ss);
        a[4] = (bf16_t)quant6(f1.x, ss); a[5] = (bf16_t)quant6(f1.y, ss);
        a[6] = (bf16_t)quant6(f1.z, ss); a[7] = (bf16_t)quant6(f1.w, ss);
        af[kc] = a;
    }
    f32x4 acc[4];
    #pragma unroll
    for (int nb = 0; nb < 4; ++nb) acc[nb] = (f32x4){0.f, 0.f, 0.f, 0.f};
    #pragma unroll
    for (int kc = 0; kc < 2; ++kc) {
        #pragma unroll
        for (int nb = 0; nb < 4; ++nb) {
            bf16x8 bfr;
            #pragma unroll
            for (int j = 0; j < 8; ++j)
                bfr[j] = (bf16_t)quant6(wbig[(size_t)(h * 64 + kc * 32 + q8 + j) * 1024 + n0 + nb * 16 + l15], sb);
            acc[nb] = __builtin_amdgcn_mfma_f32_16x16x32_bf16(af[kc], bfr, acc[nb], 0, 0, 0);
        }
    }
    #pragma unroll
    for (int nb = 0; nb < 4; ++nb)
        #pragma unroll
        for (int r = 0; r < 4; ++r)
            outp[(size_t)(h * 64 + m0 + quad * 4 + r) * 1024 + n0 + nb * 16 + l15] =
                (bf16_t)(acc[nb][r] * oscale);
}

// ---------------------------------------------------------------- GEMM  C[M,N] = A[M,K] * Bt[N,K]^T
// R15: K-loop unrolled x2 — two 64-slabs staged per barrier cycle into a double-width
// LDS buffer; one vmcnt drain covers both (loads pipeline). LDS 64KB/block, 2 blocks/CU.
template <bool OUT_F32>
__global__ __launch_bounds__(256) void gemm128(const bf16_t* __restrict__ A,
                                               const bf16_t* __restrict__ Bt,
                                               void* __restrict__ Cv,
                                               int lda, int ldb, int ldc, int K) {
    __shared__ __align__(16) bf16_t As[2 * 128 * 64];
    __shared__ __align__(16) bf16_t Bs[2 * 128 * 64];
    const int tid = threadIdx.x;
    const int w = tid >> 6, l = tid & 63;
    const int l15 = l & 15, quad = l >> 4;
    const int m0 = blockIdx.y * 128, n0 = blockIdx.x * 128;
    const int wm = (w & 1) * 64, wn = (w >> 1) * 64;

    f32x4 acc[4][4];
    #pragma unroll
    for (int a = 0; a < 4; ++a)
        #pragma unroll
        for (int b = 0; b < 4; ++b) acc[a][b] = (f32x4){0.f, 0.f, 0.f, 0.f};

    // stage one 64-slab at K-offset kc into LDS half hb
    auto STAGE = [&](int kc, int hb) {
        #pragma unroll
        for (int rep = 0; rep < 4; ++rep) {
            int ci = rep * 256 + w * 64 + l;
            int row = ci >> 3, slot = ci & 7;
            int gch = slot ^ ((row ^ (row >> 3)) & 7);
            __builtin_amdgcn_global_load_lds(
                (glb_u32*)(A + (size_t)(m0 + row) * lda + kc + gch * 8),
                (lds_u32*)(As + hb * 8192 + (rep * 256 + w * 64) * 8), 16, 0, 0);
            __builtin_amdgcn_global_load_lds(
                (glb_u32*)(Bt + (size_t)(n0 + row) * ldb + kc + gch * 8),
                (lds_u32*)(Bs + hb * 8192 + (rep * 256 + w * 64) * 8), 16, 0, 0);
        }
    };
    // consume one 64-slab from LDS half hb
    auto COMPUTE = [&](int hb) {
        #pragma unroll
        for (int kb = 0; kb < 2; ++kb) {
            bf16x8 af[4], bfr[4];
            #pragma unroll
            for (int mb = 0; mb < 4; ++mb) {
                int row = wm + mb * 16 + l15;
                int slot = ((kb << 2) + quad) ^ ((row ^ (row >> 3)) & 7);
                af[mb] = *(const bf16x8*)(As + hb * 8192 + (row << 6) + slot * 8);
            }
            #pragma unroll
            for (int nb = 0; nb < 4; ++nb) {
                int row = wn + nb * 16 + l15;
                int slot = ((kb << 2) + quad) ^ ((row ^ (row >> 3)) & 7);
                bfr[nb] = *(const bf16x8*)(Bs + hb * 8192 + (row << 6) + slot * 8);
            }
            #pragma unroll
            for (int mb = 0; mb < 4; ++mb)
                #pragma unroll
                for (int nb = 0; nb < 4; ++nb)
                    acc[mb][nb] = __builtin_amdgcn_mfma_f32_16x16x32_bf16(af[mb], bfr[nb], acc[mb][nb], 0, 0, 0);
        }
    };

    for (int kc = 0; kc < K; kc += 128) {
        const bool has2 = (kc + 64) < K;
        __syncthreads();
        STAGE(kc, 0);
        if (has2) STAGE(kc + 64, 1);
        __syncthreads();   // one drain for both slabs
        COMPUTE(0);
        if (has2) COMPUTE(1);
    }
    #pragma unroll
    for (int mb = 0; mb < 4; ++mb) {
        #pragma unroll
        for (int nb = 0; nb < 4; ++nb) {
            int col = n0 + wn + nb * 16 + l15;
            #pragma unroll
            for (int r = 0; r < 4; ++r) {
                int row = m0 + wm + mb * 16 + quad * 4 + r;
                if constexpr (OUT_F32)
                    ((float*)Cv)[(size_t)row * ldc + col] = acc[mb][nb][r];
                else
                    ((bf16_t*)Cv)[(size_t)row * ldc + col] = (bf16_t)acc[mb][nb][r];
            }
        }
    }
}

// ---------------------------------------------------------------- V transpose: QKV V-part -> Vt[bh][s][t]
__global__ __launch_bounds__(256) void vtrans_kernel(const bf16_t* __restrict__ QKV,
                                                     bf16_t* __restrict__ Vt) {
    __shared__ __align__(16) bf16_t tile[64 * 72];
    const int tid = threadIdx.x;
    const int bh = blockIdx.x >> 5, tt = blockIdx.x & 31;
    const int b = bh >> 4, h = bh & 15;
    #pragma unroll
    for (int rep = 0; rep < 2; ++rep) {
        int ci = rep * 256 + tid;
        int row = ci >> 3, ch = ci & 7;
        bf16x8 v = *(const bf16x8*)(QKV + ((size_t)(b * TT + tt * 64 + row)) * 3072 + 2048 + h * 64 + ch * 8);
        #pragma unroll
        for (int j = 0; j < 8; ++j) tile[(ch * 8 + j) * 72 + row] = v[j];
    }
    __syncthreads();
    #pragma unroll
    for (int rep = 0; rep < 2; ++rep) {
        int ci = rep * 256 + tid;
        int s = ci >> 3, ch = ci & 7;
        bf16x8 v = *(const bf16x8*)(tile + s * 72 + ch * 8);
        *(bf16x8*)(Vt + ((size_t)(bh * 64 + s)) * TT + tt * 64 + ch * 8) = v;
    }
}

// ---------------------------------------------------------------- attention (transposed scores)
// Sᵀ = mfma(K, Q): lane holds S[q = l15][kpos = c*16 + quad*4 + r].
// 4 q-tiles per block share each kb/vb fragment read. Two phases per k-tile:
//   phase 1 (kb live): per active tile: bias-init sacc, QK MFMA, exp2, P -> LDS.
//   phase 2 (vb live): per active tile: read P fragment, PV MFMA + ones row-sum.
// 16B-block swizzle on K/V/P keeps banks <=2-way.
__global__ __launch_bounds__(256, 2) void attn_kernel(const bf16_t* __restrict__ QKV,
                                                      const bf16_t* __restrict__ Vt,
                                                      const float* __restrict__ Bias,
                                                      bf16_t* __restrict__ O) {
    __shared__ __align__(16) bf16_t Ks[2 * 64 * 64];
    __shared__ __align__(16) bf16_t Vs[2 * 64 * 64];
    __shared__ __align__(16) bf16_t Ps[4 * 4 * 16 * 64];   // [wave][tile][16 q][64 k]

    const int tid = threadIdx.x;
    const int w = tid >> 6, l = tid & 63;
    const int l15 = l & 15, quad = l >> 4, q8 = quad * 8;
    const int p = (blockIdx.x >> 3) & 7;
    const int bh = (blockIdx.x & 7) + ((blockIdx.x >> 6) << 3);
    const int b = bh >> 4, h = bh & 15;
    const int qt[4] = {p, 15 - p, 16 + p, 31 - p};

    const size_t xbase = (size_t)b * TT * 3072;

    bf16x8 qa[4][2];
    #pragma unroll
    for (int t = 0; t < 4; ++t)
        #pragma unroll
        for (int kc = 0; kc < 2; ++kc)
            qa[t][kc] = *(const bf16x8*)(QKV + xbase + (size_t)(qt[t] * 64 + w * 16 + l15) * 3072 + h * 64 + kc * 32 + q8);

    bf16x8 ones;
    #pragma unroll
    for (int j = 0; j < 8; ++j) ones[j] = (bf16_t)1.0f;

    f32x4 oacc[4][4], lacc[4];
    #pragma unroll
    for (int t = 0; t < 4; ++t) {
        lacc[t] = (f32x4){0.f, 0.f, 0.f, 0.f};
        #pragma unroll
        for (int i = 0; i < 4; ++i) oacc[t][i] = (f32x4){0.f, 0.f, 0.f, 0.f};
    }
    bf16_t* Pw = Ps + w * 4096;

    // stage k-tile kt into LDS half hb (4 x global_load_lds per wave, 16B each)
    auto STAGE = [&](int kt, int hb) {
        #pragma unroll
        for (int rep = 0; rep < 2; ++rep) {
            int ci = rep * 256 + tid;
            int row = ci >> 3, slot = ci & 7;
            int gch = slot ^ ((row ^ (row >> 3)) & 7);
            __builtin_amdgcn_global_load_lds(
                (glb_u32*)(QKV + xbase + (size_t)(kt * 64 + row) * 3072 + 1024 + h * 64 + gch * 8),
                (lds_u32*)(Ks + hb * 4096 + (rep * 256 + w * 64) * 8), 16, 0, 0);
            __builtin_amdgcn_global_load_lds(
                (glb_u32*)(Vt + (size_t)bh * 131072 + (size_t)row * 2048 + kt * 64 + gch * 8),
                (lds_u32*)(Vs + hb * 4096 + (rep * 256 + w * 64) * 8), 16, 0, 0);
        }
    };

    // compute all 4 q-tiles for k-tile kt from LDS half hb
    auto COMPUTE = [&](int kt, int hb) {
        // ---- phase 1: K fragments live; QK + softmax + P store per active tile
        {
            bf16x8 kb[4][2];
            #pragma unroll
            for (int kc = 0; kc < 2; ++kc)
                #pragma unroll
                for (int c = 0; c < 4; ++c) {
                    int row = c * 16 + l15;
                    int slot = (kc * 4 + quad) ^ ((row ^ (row >> 3)) & 7);
                    kb[c][kc] = *(const bf16x8*)(Ks + hb * 4096 + row * 64 + slot * 8);
                }
            #pragma unroll
            for (int t = 0; t < 4; ++t) {
                if (kt > qt[t]) continue;   // wave-uniform
                const float* bp = Bias + ((((size_t)(qt[t] - kt) * 4 + w) * 4) * 64 + l) * 4;
                f32x4 sacc[4];
                #pragma unroll
                for (int c = 0; c < 4; ++c) sacc[c] = *(const f32x4*)(bp + c * 256);
                #pragma unroll
                for (int kc = 0; kc < 2; ++kc)
                    #pragma unroll
                    for (int c = 0; c < 4; ++c)
                        sacc[c] = __builtin_amdgcn_mfma_f32_16x16x32_bf16(kb[c][kc], qa[t][kc], sacc[c], 0, 0, 0);
                #pragma unroll
                for (int c = 0; c < 4; ++c) {
                    bf16x4 pk;
                    #pragma unroll
                    for (int r = 0; r < 4; ++r)
                        pk[r] = (bf16_t)fexp2(sacc[c][r]);   // -inf (masked) -> 0
                    int pp = (c * 2 + (quad >> 1)) ^ (l15 & 7);
                    *(bf16x4*)(Pw + t * 1024 + l15 * 64 + pp * 8 + (quad & 1) * 4) = pk;
                }
            }
        }
        __builtin_amdgcn_wave_barrier();
        // ---- phase 2: V fragments live; PV + ones row-sum per active tile
        {
            bf16x8 vb[4][2];
            #pragma unroll
            for (int kc = 0; kc < 2; ++kc)
                #pragma unroll
                for (int c = 0; c < 4; ++c) {
                    int row = c * 16 + l15;
                    int slot = (kc * 4 + quad) ^ ((row ^ (row >> 3)) & 7);
                    vb[c][kc] = *(const bf16x8*)(Vs + hb * 4096 + row * 64 + slot * 8);
                }
            #pragma unroll
            for (int t = 0; t < 4; ++t) {
                if (kt > qt[t]) continue;
                #pragma unroll
                for (int kc = 0; kc < 2; ++kc) {
                    bf16x8 pa = *(const bf16x8*)(Pw + t * 1024 + l15 * 64 + (((kc * 4 + quad) ^ (l15 & 7)) * 8));
                    #pragma unroll
                    for (int sb = 0; sb < 4; ++sb)
                        oacc[t][sb] = __builtin_amdgcn_mfma_f32_16x16x32_bf16(pa, vb[sb][kc], oacc[t][sb], 0, 0, 0);
                    lacc[t] = __builtin_amdgcn_mfma_f32_16x16x32_bf16(pa, ones, lacc[t], 0, 0, 0);
                }
            }
        }
        __builtin_amdgcn_wave_barrier();
    };

    const int nkt = qt[3] + 1;   // 32 - p
    for (int kt2 = 0; kt2 < nkt; kt2 += 2) {
        const bool has2 = (kt2 + 1) < nkt;
        // Barrier 1: all waves finished reading both halves of the previous pair.
        __syncthreads();
        STAGE(kt2, 0);
        if (has2) STAGE(kt2 + 1, 1);
        // Barrier 2: one vmcnt drain covers BOTH tiles' loads (they pipeline).
        __syncthreads();
        COMPUTE(kt2, 0);
        if (has2) COMPUTE(kt2 + 1, 1);
    }

    // epilogue: lacc[t][r] holds the full denominator for row q = quad*4+r of tile t.
    #pragma unroll
    for (int t = 0; t < 4; ++t) {
        #pragma unroll
        for (int r = 0; r < 4; ++r) {
            float invr = 1.0f / lacc[t][r];
            #pragma unroll
            for (int sb = 0; sb < 4; ++sb) {
                int q = qt[t] * 64 + w * 16 + quad * 4 + r;
                int col = h * 64 + sb * 16 + l15;
                O[(size_t)(b * TT + q) * DD + col] = (bf16_t)(oacc[t][sb][r] * invr);
            }
        }
    }
}

// ---------------------------------------------------------------- launch
extern "C" void kernel_launch(void* const* d_in, const int* in_sizes, int n_in,
                              void* d_out, int out_size, void* d_ws, size_t ws_size,
                              hipStream_t stream) {
    const float* x   = (const float*)d_in[0];
    const float* wq  = (const float*)d_in[1];
    const float* wk  = (const float*)d_in[2];
    const float* wv  = (const float*)d_in[3];
    const float* wo  = (const float*)d_in[4];
    const float* wu  = (const float*)d_in[5];
    const float* wsv = (const float*)d_in[6];
    const float* psc = (const float*)d_in[7];
    float* out = (float*)d_out;

    char* ws = (char*)d_ws;
    float*  amax  = (float*)(ws);
    bf16_t* W_all = (bf16_t*)(ws + 256);                       // 3072x1024 bf16 (6291456 B)
    bf16_t* Wo    = (bf16_t*)(ws + 6291712);                   // 1024x1024 bf16 (2097152 B)
    bf16_t* xb    = (bf16_t*)(ws + 8388864);                   // 8192x1024 bf16 (16777216 B)
    bf16_t* Obuf  = xb;                                        // reuse: xb dead after GEMM1
    bf16_t* QKV   = (bf16_t*)(ws + 25166080);                  // 8192x3072 bf16 (50331648 B)
    bf16_t* Vt    = (bf16_t*)(ws + 75497728);                  // 64bh x 64s x 2048t bf16 (16777216 B)
    float*  Bias  = (float*)(ws + 92274944);                   // 128 x 1024 f32 (524288 B)

    hipLaunchKernelGGL(ptable_kernel, dim3(128), dim3(256), 0, stream, psc, Bias);
    hipLaunchKernelGGL(absmax6, dim3(64, 6), dim3(256), 0, stream, wq, wk, wv, wo, wu, wsv, amax);
    hipLaunchKernelGGL(prep_w, dim3(768, 2), dim3(256), 0, stream,
                       wq, wk, wv, wo, wu, wsv, amax, W_all, Wo);
    hipLaunchKernelGGL(xcvt_kernel, dim3(4096), dim3(256), 0, stream, x, xb);

    // GEMM1: QKV = xb @ W_all^T   (M=8192, N=3072, K=1024)
    hipLaunchKernelGGL((gemm128<false>), dim3(24, 64), dim3(256), 0, stream,
                       xb, W_all, (void*)QKV, 1024, 1024, 3072, 1024);

    // V transpose
    hipLaunchKernelGGL(vtrans_kernel, dim3(2048), dim3(256), 0, stream, QKV, Vt);

    // attention (512 blocks: bh x 8 tile-quads, XCD-swizzled; exactly 2 blocks/CU)
    hipLaunchKernelGGL(attn_kernel, dim3(512), dim3(256), 0, stream, QKV, Vt, Bias, Obuf);

    // GEMM2: out = O @ Wo^T   (M=8192, N=1024, K=1024)
    hipLaunchKernelGGL((gemm128<true>), dim3(8, 64), dim3(256), 0, stream,
                       Obuf, Wo, (void*)out, 1024, 1024, 1024, 1024);
}

// Round 12
// 262.794 us; speedup vs baseline: 1.0276x; 1.0276x over previous
//
#include <hip/hip_runtime.h>
#include <hip/hip_bf16.h>
#include <stdint.h>

// SheafAttention on MI355X (gfx950).  B=4, T=2048, D=1024, H=16, S=64.
//
// Pipeline:
//  1. pre_kernel (FUSED R16): xcvt (x->bf16) + ptable (p-adic bias tiles) + absmax6,
//     one launch, 1-D grid partition [0,4096)=xcvt [4096,4224)=ptable [4224,4608)=absmax.
//  2. prep_w (quant + stalk-fold; Q pre-scaled 0.125*log2e)
//  3. gemm128: QKV = xb @ W_all^T.  R16: REVERTED to single-buffer 32KB LDS — R15's
//     x2 K-unroll doubled LDS to 64KB and halved occupancy (4->2 blocks/CU, gemm
//     68->71us). Drain-amortization only pays when occupancy is register-pinned
//     (attn); GEMM was LDS-elastic.
//  4. vtrans: V part of QKV -> Vt[bh][s][t]
//  5. attn (R14 structure): 4 q-tiles/block {p,15-p,16+p,31-p} share each kb/vb
//     fragment read; two-phase per k-tile (K-frags then V-frags); bias C-init from
//     table; ones-MFMA row-sum; x2 stage unroll, one drain per 2 k-tiles.
//     OCCUPANCY AXIS CLOSED for attn (R10-R12): ~168 unified regs => 2 waves/SIMD;
//     (256,4)/cap128 and (256,3) variants all spilled or lost sharing. STAY (256,2).
//     TRIPWIRE: attn WRITE_SIZE must stay ~16MB.
//  6. gemm128: out = O @ Wo^T (fp32).
//
// R17 = R16 resubmitted verbatim: R16 bench failed with GPUAcquisitionTimeout
// (infra, no measurement). Predictions from R16 stand.

typedef __bf16 bf16_t;
typedef __attribute__((ext_vector_type(4))) __bf16 bf16x4;
typedef __attribute__((ext_vector_type(8))) __bf16 bf16x8;
typedef __attribute__((ext_vector_type(4))) float f32x4;

#define BB 4
#define TT 2048
#define DD 1024
#define HH 16
#define SS 64

__device__ __forceinline__ float quant6(float v, float s) {
    float q = rintf(v / s);
    q = fminf(fmaxf(q, -31.0f), 31.0f);
    return q * s;
}

__device__ __forceinline__ float fexp2(float x) {
#if __has_builtin(__builtin_amdgcn_exp2f)
    return __builtin_amdgcn_exp2f(x);
#else
    return exp2f(x);
#endif
}

typedef __attribute__((address_space(3))) uint32_t lds_u32;
typedef const __attribute__((address_space(1))) uint32_t glb_u32;

// ---------------------------------------------------------------- fused prologue
// blocks [0,4096):      xcvt  — x fp32 -> xb bf16 (8 elem/thread)
// blocks [4096,4224):   ptable — bias tbl[((e*4+c)*64+lane)*4+r], e=(qt-kt)*4+wave;
//                        d = e*16 + (lane&15) - (c*16 + (lane>>4)*4 + r);
//                        d<0 -> -inf, d==0 -> pb2*16, else pb2*ctz(d)
// blocks [4224,4608):    absmax6 — 64 blocks per tensor, atomicMax on float bits
//                        (0xAA workspace poison is a negative int: safe identity)
__global__ __launch_bounds__(256) void pre_kernel(const float* __restrict__ x,
                                                  bf16_t* __restrict__ xb,
                                                  const float* __restrict__ psc,
                                                  float* __restrict__ tbl,
                                                  const float* __restrict__ wq,
                                                  const float* __restrict__ wk,
                                                  const float* __restrict__ wv,
                                                  const float* __restrict__ wo,
                                                  const float* __restrict__ wu,
                                                  const float* __restrict__ wsv,
                                                  float* __restrict__ amax) {
    const int bid = blockIdx.x;
    const int tid = threadIdx.x;
    if (bid < 4096) {                       // ---- xcvt
        int i = (bid * 256 + tid) * 8;
        float4 f0 = *(const float4*)(x + i);
        float4 f1 = *(const float4*)(x + i + 4);
        bf16x8 v;
        v[0] = (bf16_t)f0.x; v[1] = (bf16_t)f0.y; v[2] = (bf16_t)f0.z; v[3] = (bf16_t)f0.w;
        v[4] = (bf16_t)f1.x; v[5] = (bf16_t)f1.y; v[6] = (bf16_t)f1.z; v[7] = (bf16_t)f1.w;
        *(bf16x8*)(xb + i) = v;
        return;
    }
    if (bid < 4224) {                       // ---- ptable
        const int idx = (bid - 4096) * 256 + tid;   // 32768 total
        const int l = idx & 63, c = (idx >> 6) & 3, e = idx >> 8;
        const int l15 = l & 15, quad = l >> 4;
        const float pb2 = psc[0] * 1.44269504089f * 0.0625f;
        f32x4 v;
        #pragma unroll
        for (int r = 0; r < 4; ++r) {
            const int d = e * 16 + l15 - (c * 16 + quad * 4 + r);
            float val;
            if (d < 0) val = -INFINITY;
            else if (d == 0) val = pb2 * 16.0f;
            else val = pb2 * (float)__builtin_ctz((unsigned)d);
            v[r] = val;
        }
        *(f32x4*)(tbl + (size_t)idx * 4) = v;
        return;
    }
    // ---- absmax6
    const int t = (bid - 4224) >> 6;
    const int j = (bid - 4224) & 63;
    const float* src = (t == 0) ? wq : (t == 1) ? wk : (t == 2) ? wv
                     : (t == 3) ? wo : (t == 4) ? wu : wsv;
    const int n4 = (t < 4) ? (1048576 / 4) : (4096 / 4);
    float m = 0.0f;
    for (int i = j * 256 + tid; i < n4; i += 64 * 256) {
        float4 v = ((const float4*)src)[i];
        m = fmaxf(m, fmaxf(fmaxf(fabsf(v.x), fabsf(v.y)), fmaxf(fabsf(v.z), fabsf(v.w))));
    }
    #pragma unroll
    for (int mask = 32; mask > 0; mask >>= 1)
        m = fmaxf(m, __shfl_xor(m, mask));
    __shared__ float red[4];
    int w = tid >> 6;
    if ((tid & 63) == 0) red[w] = m;
    __syncthreads();
    if (tid == 0) {
        m = fmaxf(fmaxf(red[0], red[1]), fmaxf(red[2], red[3]));
        atomicMax((int*)(amax + t), __float_as_int(m));
    }
}

// ---------------------------------------------------------------- weight prep (quant + fold)
__global__ __launch_bounds__(256) void prep_w(const float* __restrict__ wq,
                                              const float* __restrict__ wk,
                                              const float* __restrict__ wv,
                                              const float* __restrict__ wo,
                                              const float* __restrict__ wu,
                                              const float* __restrict__ wsv,
                                              const float* __restrict__ amax,
                                              bf16_t* __restrict__ W_all,
                                              bf16_t* __restrict__ Wo) {
    const int which = blockIdx.y;
    if (blockIdx.x < 512) {
        const float* src = which ? wo : wv;
        bf16_t* dst = which ? Wo : (W_all + (size_t)2048 * 1024);
        float s = amax[which ? 3 : 2] / 31.0f + 1e-8f;
        int i = (blockIdx.x * 256 + threadIdx.x) * 8;
        float4 f0 = *(const float4*)(src + i);
        float4 f1 = *(const float4*)(src + i + 4);
        bf16x8 v;
        v[0] = (bf16_t)quant6(f0.x, s); v[1] = (bf16_t)quant6(f0.y, s);
        v[2] = (bf16_t)quant6(f0.z, s); v[3] = (bf16_t)quant6(f0.w, s);
        v[4] = (bf16_t)quant6(f1.x, s); v[5] = (bf16_t)quant6(f1.y, s);
        v[6] = (bf16_t)quant6(f1.z, s); v[7] = (bf16_t)quant6(f1.w, s);
        *(bf16x8*)(dst + i) = v;
        return;
    }
    const int fx = blockIdx.x - 512;
    const float* wbig = which ? wk : wq;
    const float* wsml = which ? wsv : wu;
    const float sb = amax[which ? 1 : 0] / 31.0f + 1e-8f;
    const float ss = amax[which ? 5 : 4] / 31.0f + 1e-8f;
    const float oscale = which ? 1.0f : 0.125f * 1.44269504089f;
    bf16_t* outp = W_all + (size_t)which * 1024 * 1024;
    const int h = fx >> 4, n0 = (fx & 15) * 64;
    const int w = threadIdx.x >> 6, l = threadIdx.x & 63;
    const int l15 = l & 15, quad = l >> 4, q8 = quad * 8;
    const int m0 = w * 16;

    bf16x8 af[2];
    #pragma unroll
    for (int kc = 0; kc < 2; ++kc) {
        const float* src = wsml + (m0 + l15) * 64 + kc * 32 + q8;
        float4 f0 = *(const float4*)(src);
        float4 f1 = *(const float4*)(src + 4);
        bf16x8 a;
        a[0] = (bf16_t)quant6(f0.x, ss); a[1] = (bf16_t)quant6(f0.y, ss);
        a[2] = (bf16_t)quant6(f0.z, ss); a[3] = (bf16_t)quant6(f0.w, ss);
        a[4] = (bf16_t)quant6(f1.x, ss); a[5] = (bf16_t)quant6(f1.y, ss);
        a[6] = (bf16_t)quant6(f1.z, ss); a[7] = (bf16_t)quant6(f1.w, ss);
        af[kc] = a;
    }
    f32x4 acc[4];
    #pragma unroll
    for (int nb = 0; nb < 4; ++nb) acc[nb] = (f32x4){0.f, 0.f, 0.f, 0.f};
    #pragma unroll
    for (int kc = 0; kc < 2; ++kc) {
        #pragma unroll
        for (int nb = 0; nb < 4; ++nb) {
            bf16x8 bfr;
            #pragma unroll
            for (int j = 0; j < 8; ++j)
                bfr[j] = (bf16_t)quant6(wbig[(size_t)(h * 64 + kc * 32 + q8 + j) * 1024 + n0 + nb * 16 + l15], sb);
            acc[nb] = __builtin_amdgcn_mfma_f32_16x16x32_bf16(af[kc], bfr, acc[nb], 0, 0, 0);
        }
    }
    #pragma unroll
    for (int nb = 0; nb < 4; ++nb)
        #pragma unroll
        for (int r = 0; r < 4; ++r)
            outp[(size_t)(h * 64 + m0 + quad * 4 + r) * 1024 + n0 + nb * 16 + l15] =
                (bf16_t)(acc[nb][r] * oscale);
}

// ---------------------------------------------------------------- GEMM  C[M,N] = A[M,K] * Bt[N,K]^T
// Single-buffer 32KB LDS (R14-proven): 4 blocks/CU occupancy beats drain amortization.
template <bool OUT_F32>
__global__ __launch_bounds__(256) void gemm128(const bf16_t* __restrict__ A,
                                               const bf16_t* __restrict__ Bt,
                                               void* __restrict__ Cv,
                                               int lda, int ldb, int ldc, int K) {
    __shared__ __align__(16) bf16_t As[128 * 64];
    __shared__ __align__(16) bf16_t Bs[128 * 64];
    const int tid = threadIdx.x;
    const int w = tid >> 6, l = tid & 63;
    const int l15 = l & 15, quad = l >> 4;
    const int m0 = blockIdx.y * 128, n0 = blockIdx.x * 128;
    const int wm = (w & 1) * 64, wn = (w >> 1) * 64;

    f32x4 acc[4][4];
    #pragma unroll
    for (int a = 0; a < 4; ++a)
        #pragma unroll
        for (int b = 0; b < 4; ++b) acc[a][b] = (f32x4){0.f, 0.f, 0.f, 0.f};

    for (int kc = 0; kc < K; kc += 64) {
        __syncthreads();
        #pragma unroll
        for (int rep = 0; rep < 4; ++rep) {
            int ci = rep * 256 + w * 64 + l;
            int row = ci >> 3, slot = ci & 7;
            int gch = slot ^ ((row ^ (row >> 3)) & 7);
            __builtin_amdgcn_global_load_lds(
                (glb_u32*)(A + (size_t)(m0 + row) * lda + kc + gch * 8),
                (lds_u32*)(As + (rep * 256 + w * 64) * 8), 16, 0, 0);
            __builtin_amdgcn_global_load_lds(
                (glb_u32*)(Bt + (size_t)(n0 + row) * ldb + kc + gch * 8),
                (lds_u32*)(Bs + (rep * 256 + w * 64) * 8), 16, 0, 0);
        }
        __syncthreads();
        #pragma unroll
        for (int kb = 0; kb < 2; ++kb) {
            bf16x8 af[4], bfr[4];
            #pragma unroll
            for (int mb = 0; mb < 4; ++mb) {
                int row = wm + mb * 16 + l15;
                int slot = ((kb << 2) + quad) ^ ((row ^ (row >> 3)) & 7);
                af[mb] = *(const bf16x8*)(As + (row << 6) + slot * 8);
            }
            #pragma unroll
            for (int nb = 0; nb < 4; ++nb) {
                int row = wn + nb * 16 + l15;
                int slot = ((kb << 2) + quad) ^ ((row ^ (row >> 3)) & 7);
                bfr[nb] = *(const bf16x8*)(Bs + (row << 6) + slot * 8);
            }
            #pragma unroll
            for (int mb = 0; mb < 4; ++mb)
                #pragma unroll
                for (int nb = 0; nb < 4; ++nb)
                    acc[mb][nb] = __builtin_amdgcn_mfma_f32_16x16x32_bf16(af[mb], bfr[nb], acc[mb][nb], 0, 0, 0);
        }
    }
    #pragma unroll
    for (int mb = 0; mb < 4; ++mb) {
        #pragma unroll
        for (int nb = 0; nb < 4; ++nb) {
            int col = n0 + wn + nb * 16 + l15;
            #pragma unroll
            for (int r = 0; r < 4; ++r) {
                int row = m0 + wm + mb * 16 + quad * 4 + r;
                if constexpr (OUT_F32)
                    ((float*)Cv)[(size_t)row * ldc + col] = acc[mb][nb][r];
                else
                    ((bf16_t*)Cv)[(size_t)row * ldc + col] = (bf16_t)acc[mb][nb][r];
            }
        }
    }
}

// ---------------------------------------------------------------- V transpose: QKV V-part -> Vt[bh][s][t]
__global__ __launch_bounds__(256) void vtrans_kernel(const bf16_t* __restrict__ QKV,
                                                     bf16_t* __restrict__ Vt) {
    __shared__ __align__(16) bf16_t tile[64 * 72];
    const int tid = threadIdx.x;
    const int bh = blockIdx.x >> 5, tt = blockIdx.x & 31;
    const int b = bh >> 4, h = bh & 15;
    #pragma unroll
    for (int rep = 0; rep < 2; ++rep) {
        int ci = rep * 256 + tid;
        int row = ci >> 3, ch = ci & 7;
        bf16x8 v = *(const bf16x8*)(QKV + ((size_t)(b * TT + tt * 64 + row)) * 3072 + 2048 + h * 64 + ch * 8);
        #pragma unroll
        for (int j = 0; j < 8; ++j) tile[(ch * 8 + j) * 72 + row] = v[j];
    }
    __syncthreads();
    #pragma unroll
    for (int rep = 0; rep < 2; ++rep) {
        int ci = rep * 256 + tid;
        int s = ci >> 3, ch = ci & 7;
        bf16x8 v = *(const bf16x8*)(tile + s * 72 + ch * 8);
        *(bf16x8*)(Vt + ((size_t)(bh * 64 + s)) * TT + tt * 64 + ch * 8) = v;
    }
}

// ---------------------------------------------------------------- attention (transposed scores)
// Sᵀ = mfma(K, Q): lane holds S[q = l15][kpos = c*16 + quad*4 + r].
// 4 q-tiles per block share each kb/vb fragment read. Two phases per k-tile:
//   phase 1 (kb live): per active tile: bias-init sacc, QK MFMA, exp2, P -> LDS.
//   phase 2 (vb live): per active tile: read P fragment, PV MFMA + ones row-sum.
// 16B-block swizzle on K/V/P keeps banks <=2-way.
__global__ __launch_bounds__(256, 2) void attn_kernel(const bf16_t* __restrict__ QKV,
                                                      const bf16_t* __restrict__ Vt,
                                                      const float* __restrict__ Bias,
                                                      bf16_t* __restrict__ O) {
    __shared__ __align__(16) bf16_t Ks[2 * 64 * 64];
    __shared__ __align__(16) bf16_t Vs[2 * 64 * 64];
    __shared__ __align__(16) bf16_t Ps[4 * 4 * 16 * 64];   // [wave][tile][16 q][64 k]

    const int tid = threadIdx.x;
    const int w = tid >> 6, l = tid & 63;
    const int l15 = l & 15, quad = l >> 4, q8 = quad * 8;
    const int p = (blockIdx.x >> 3) & 7;
    const int bh = (blockIdx.x & 7) + ((blockIdx.x >> 6) << 3);
    const int b = bh >> 4, h = bh & 15;
    const int qt[4] = {p, 15 - p, 16 + p, 31 - p};

    const size_t xbase = (size_t)b * TT * 3072;

    bf16x8 qa[4][2];
    #pragma unroll
    for (int t = 0; t < 4; ++t)
        #pragma unroll
        for (int kc = 0; kc < 2; ++kc)
            qa[t][kc] = *(const bf16x8*)(QKV + xbase + (size_t)(qt[t] * 64 + w * 16 + l15) * 3072 + h * 64 + kc * 32 + q8);

    bf16x8 ones;
    #pragma unroll
    for (int j = 0; j < 8; ++j) ones[j] = (bf16_t)1.0f;

    f32x4 oacc[4][4], lacc[4];
    #pragma unroll
    for (int t = 0; t < 4; ++t) {
        lacc[t] = (f32x4){0.f, 0.f, 0.f, 0.f};
        #pragma unroll
        for (int i = 0; i < 4; ++i) oacc[t][i] = (f32x4){0.f, 0.f, 0.f, 0.f};
    }
    bf16_t* Pw = Ps + w * 4096;

    // stage k-tile kt into LDS half hb (4 x global_load_lds per wave, 16B each)
    auto STAGE = [&](int kt, int hb) {
        #pragma unroll
        for (int rep = 0; rep < 2; ++rep) {
            int ci = rep * 256 + tid;
            int row = ci >> 3, slot = ci & 7;
            int gch = slot ^ ((row ^ (row >> 3)) & 7);
            __builtin_amdgcn_global_load_lds(
                (glb_u32*)(QKV + xbase + (size_t)(kt * 64 + row) * 3072 + 1024 + h * 64 + gch * 8),
                (lds_u32*)(Ks + hb * 4096 + (rep * 256 + w * 64) * 8), 16, 0, 0);
            __builtin_amdgcn_global_load_lds(
                (glb_u32*)(Vt + (size_t)bh * 131072 + (size_t)row * 2048 + kt * 64 + gch * 8),
                (lds_u32*)(Vs + hb * 4096 + (rep * 256 + w * 64) * 8), 16, 0, 0);
        }
    };

    // compute all 4 q-tiles for k-tile kt from LDS half hb
    auto COMPUTE = [&](int kt, int hb) {
        // ---- phase 1: K fragments live; QK + softmax + P store per active tile
        {
            bf16x8 kb[4][2];
            #pragma unroll
            for (int kc = 0; kc < 2; ++kc)
                #pragma unroll
                for (int c = 0; c < 4; ++c) {
                    int row = c * 16 + l15;
                    int slot = (kc * 4 + quad) ^ ((row ^ (row >> 3)) & 7);
                    kb[c][kc] = *(const bf16x8*)(Ks + hb * 4096 + row * 64 + slot * 8);
                }
            #pragma unroll
            for (int t = 0; t < 4; ++t) {
                if (kt > qt[t]) continue;   // wave-uniform
                const float* bp = Bias + ((((size_t)(qt[t] - kt) * 4 + w) * 4) * 64 + l) * 4;
                f32x4 sacc[4];
                #pragma unroll
                for (int c = 0; c < 4; ++c) sacc[c] = *(const f32x4*)(bp + c * 256);
                #pragma unroll
                for (int kc = 0; kc < 2; ++kc)
                    #pragma unroll
                    for (int c = 0; c < 4; ++c)
                        sacc[c] = __builtin_amdgcn_mfma_f32_16x16x32_bf16(kb[c][kc], qa[t][kc], sacc[c], 0, 0, 0);
                #pragma unroll
                for (int c = 0; c < 4; ++c) {
                    bf16x4 pk;
                    #pragma unroll
                    for (int r = 0; r < 4; ++r)
                        pk[r] = (bf16_t)fexp2(sacc[c][r]);   // -inf (masked) -> 0
                    int pp = (c * 2 + (quad >> 1)) ^ (l15 & 7);
                    *(bf16x4*)(Pw + t * 1024 + l15 * 64 + pp * 8 + (quad & 1) * 4) = pk;
                }
            }
        }
        __builtin_amdgcn_wave_barrier();
        // ---- phase 2: V fragments live; PV + ones row-sum per active tile
        {
            bf16x8 vb[4][2];
            #pragma unroll
            for (int kc = 0; kc < 2; ++kc)
                #pragma unroll
                for (int c = 0; c < 4; ++c) {
                    int row = c * 16 + l15;
                    int slot = (kc * 4 + quad) ^ ((row ^ (row >> 3)) & 7);
                    vb[c][kc] = *(const bf16x8*)(Vs + hb * 4096 + row * 64 + slot * 8);
                }
            #pragma unroll
            for (int t = 0; t < 4; ++t) {
                if (kt > qt[t]) continue;
                #pragma unroll
                for (int kc = 0; kc < 2; ++kc) {
                    bf16x8 pa = *(const bf16x8*)(Pw + t * 1024 + l15 * 64 + (((kc * 4 + quad) ^ (l15 & 7)) * 8));
                    #pragma unroll
                    for (int sb = 0; sb < 4; ++sb)
                        oacc[t][sb] = __builtin_amdgcn_mfma_f32_16x16x32_bf16(pa, vb[sb][kc], oacc[t][sb], 0, 0, 0);
                    lacc[t] = __builtin_amdgcn_mfma_f32_16x16x32_bf16(pa, ones, lacc[t], 0, 0, 0);
                }
            }
        }
        __builtin_amdgcn_wave_barrier();
    };

    const int nkt = qt[3] + 1;   // 32 - p
    for (int kt2 = 0; kt2 < nkt; kt2 += 2) {
        const bool has2 = (kt2 + 1) < nkt;
        // Barrier 1: all waves finished reading both halves of the previous pair.
        __syncthreads();
        STAGE(kt2, 0);
        if (has2) STAGE(kt2 + 1, 1);
        // Barrier 2: one vmcnt drain covers BOTH tiles' loads (they pipeline).
        __syncthreads();
        COMPUTE(kt2, 0);
        if (has2) COMPUTE(kt2 + 1, 1);
    }

    // epilogue: lacc[t][r] holds the full denominator for row q = quad*4+r of tile t.
    #pragma unroll
    for (int t = 0; t < 4; ++t) {
        #pragma unroll
        for (int r = 0; r < 4; ++r) {
            float invr = 1.0f / lacc[t][r];
            #pragma unroll
            for (int sb = 0; sb < 4; ++sb) {
                int q = qt[t] * 64 + w * 16 + quad * 4 + r;
                int col = h * 64 + sb * 16 + l15;
                O[(size_t)(b * TT + q) * DD + col] = (bf16_t)(oacc[t][sb][r] * invr);
            }
        }
    }
}

// ---------------------------------------------------------------- launch
extern "C" void kernel_launch(void* const* d_in, const int* in_sizes, int n_in,
                              void* d_out, int out_size, void* d_ws, size_t ws_size,
                              hipStream_t stream) {
    const float* x   = (const float*)d_in[0];
    const float* wq  = (const float*)d_in[1];
    const float* wk  = (const float*)d_in[2];
    const float* wv  = (const float*)d_in[3];
    const float* wo  = (const float*)d_in[4];
    const float* wu  = (const float*)d_in[5];
    const float* wsv = (const float*)d_in[6];
    const float* psc = (const float*)d_in[7];
    float* out = (float*)d_out;

    char* ws = (char*)d_ws;
    float*  amax  = (float*)(ws);
    bf16_t* W_all = (bf16_t*)(ws + 256);                       // 3072x1024 bf16 (6291456 B)
    bf16_t* Wo    = (bf16_t*)(ws + 6291712);                   // 1024x1024 bf16 (2097152 B)
    bf16_t* xb    = (bf16_t*)(ws + 8388864);                   // 8192x1024 bf16 (16777216 B)
    bf16_t* Obuf  = xb;                                        // reuse: xb dead after GEMM1
    bf16_t* QKV   = (bf16_t*)(ws + 25166080);                  // 8192x3072 bf16 (50331648 B)
    bf16_t* Vt    = (bf16_t*)(ws + 75497728);                  // 64bh x 64s x 2048t bf16 (16777216 B)
    float*  Bias  = (float*)(ws + 92274944);                   // 128 x 1024 f32 (524288 B)

    // fused prologue: xcvt + ptable + absmax6 (one launch)
    hipLaunchKernelGGL(pre_kernel, dim3(4608), dim3(256), 0, stream,
                       x, xb, psc, Bias, wq, wk, wv, wo, wu, wsv, amax);
    hipLaunchKernelGGL(prep_w, dim3(768, 2), dim3(256), 0, stream,
                       wq, wk, wv, wo, wu, wsv, amax, W_all, Wo);

    // GEMM1: QKV = xb @ W_all^T   (M=8192, N=3072, K=1024)
    hipLaunchKernelGGL((gemm128<false>), dim3(24, 64), dim3(256), 0, stream,
                       xb, W_all, (void*)QKV, 1024, 1024, 3072, 1024);

    // V transpose
    hipLaunchKernelGGL(vtrans_kernel, dim3(2048), dim3(256), 0, stream, QKV, Vt);

    // attention (512 blocks: bh x 8 tile-quads, XCD-swizzled; exactly 2 blocks/CU)
    hipLaunchKernelGGL(attn_kernel, dim3(512), dim3(256), 0, stream, QKV, Vt, Bias, Obuf);

    // GEMM2: out = O @ Wo^T   (M=8192, N=1024, K=1024)
    hipLaunchKernelGGL((gemm128<true>), dim3(8, 64), dim3(256), 0, stream,
                       Obuf, Wo, (void*)out, 1024, 1024, 1024, 1024);
}

// Round 13
// 257.994 us; speedup vs baseline: 1.0468x; 1.0186x over previous
//
#include <hip/hip_runtime.h>
#include <hip/hip_bf16.h>
#include <stdint.h>

// SheafAttention on MI355X (gfx950).  B=4, T=2048, D=1024, H=16, S=64.
//
// Pipeline:
//  1. pre_kernel (fused): xcvt (x->bf16) + ptable (p-adic bias tiles) + absmax6.
//  2. prep_w (quant + stalk-fold; Q pre-scaled 0.125*log2e)
//  3. gemm128<FUSE_VT>: QKV = xb @ W_all^T; V-column tiles (n0>=2048) are written
//     DIRECTLY to Vt[bh][s][t] from the accumulator (acc[..][r] over r = 4 consecutive
//     t at fixed s -> bf16x4 stores) and skip the QKV store.  R18: this deletes the
//     vtrans kernel and 48MB of HBM round-trip.  Single-buffer 32KB LDS (R15's 64KB
//     dbuf halved occupancy 4->2 blocks/CU and LOST: drain-amortization only pays
//     when occupancy is register-pinned, like attn).
//  4. attn (R14 structure): 4 q-tiles/block {p,15-p,16+p,31-p} share each kb/vb
//     fragment read; two-phase per k-tile (K-frags then V-frags); bias C-init from
//     table; ones-MFMA row-sum; x2 stage unroll, one drain per 2 k-tiles.
//     OCCUPANCY AXIS CLOSED for attn (R10-R12): ~168 unified regs => 2 waves/SIMD;
//     (256,4)/cap128 and (256,3) variants all spilled or lost sharing. STAY (256,2).
//     TRIPWIRE: attn WRITE_SIZE must stay ~16MB.
//  5. gemm128: out = O @ Wo^T (fp32).

typedef __bf16 bf16_t;
typedef __attribute__((ext_vector_type(4))) __bf16 bf16x4;
typedef __attribute__((ext_vector_type(8))) __bf16 bf16x8;
typedef __attribute__((ext_vector_type(4))) float f32x4;

#define BB 4
#define TT 2048
#define DD 1024
#define HH 16
#define SS 64

__device__ __forceinline__ float quant6(float v, float s) {
    float q = rintf(v / s);
    q = fminf(fmaxf(q, -31.0f), 31.0f);
    return q * s;
}

__device__ __forceinline__ float fexp2(float x) {
#if __has_builtin(__builtin_amdgcn_exp2f)
    return __builtin_amdgcn_exp2f(x);
#else
    return exp2f(x);
#endif
}

typedef __attribute__((address_space(3))) uint32_t lds_u32;
typedef const __attribute__((address_space(1))) uint32_t glb_u32;

// ---------------------------------------------------------------- fused prologue
// blocks [0,4096):      xcvt  — x fp32 -> xb bf16 (8 elem/thread)
// blocks [4096,4224):   ptable — bias tbl[((e*4+c)*64+lane)*4+r], e=(qt-kt)*4+wave;
//                        d = e*16 + (lane&15) - (c*16 + (lane>>4)*4 + r);
//                        d<0 -> -inf, d==0 -> pb2*16, else pb2*ctz(d)
// blocks [4224,4608):    absmax6 — 64 blocks per tensor, atomicMax on float bits
//                        (0xAA workspace poison is a negative int: safe identity)
__global__ __launch_bounds__(256) void pre_kernel(const float* __restrict__ x,
                                                  bf16_t* __restrict__ xb,
                                                  const float* __restrict__ psc,
                                                  float* __restrict__ tbl,
                                                  const float* __restrict__ wq,
                                                  const float* __restrict__ wk,
                                                  const float* __restrict__ wv,
                                                  const float* __restrict__ wo,
                                                  const float* __restrict__ wu,
                                                  const float* __restrict__ wsv,
                                                  float* __restrict__ amax) {
    const int bid = blockIdx.x;
    const int tid = threadIdx.x;
    if (bid < 4096) {                       // ---- xcvt
        int i = (bid * 256 + tid) * 8;
        float4 f0 = *(const float4*)(x + i);
        float4 f1 = *(const float4*)(x + i + 4);
        bf16x8 v;
        v[0] = (bf16_t)f0.x; v[1] = (bf16_t)f0.y; v[2] = (bf16_t)f0.z; v[3] = (bf16_t)f0.w;
        v[4] = (bf16_t)f1.x; v[5] = (bf16_t)f1.y; v[6] = (bf16_t)f1.z; v[7] = (bf16_t)f1.w;
        *(bf16x8*)(xb + i) = v;
        return;
    }
    if (bid < 4224) {                       // ---- ptable
        const int idx = (bid - 4096) * 256 + tid;   // 32768 total
        const int l = idx & 63, c = (idx >> 6) & 3, e = idx >> 8;
        const int l15 = l & 15, quad = l >> 4;
        const float pb2 = psc[0] * 1.44269504089f * 0.0625f;
        f32x4 v;
        #pragma unroll
        for (int r = 0; r < 4; ++r) {
            const int d = e * 16 + l15 - (c * 16 + quad * 4 + r);
            float val;
            if (d < 0) val = -INFINITY;
            else if (d == 0) val = pb2 * 16.0f;
            else val = pb2 * (float)__builtin_ctz((unsigned)d);
            v[r] = val;
        }
        *(f32x4*)(tbl + (size_t)idx * 4) = v;
        return;
    }
    // ---- absmax6
    const int t = (bid - 4224) >> 6;
    const int j = (bid - 4224) & 63;
    const float* src = (t == 0) ? wq : (t == 1) ? wk : (t == 2) ? wv
                     : (t == 3) ? wo : (t == 4) ? wu : wsv;
    const int n4 = (t < 4) ? (1048576 / 4) : (4096 / 4);
    float m = 0.0f;
    for (int i = j * 256 + tid; i < n4; i += 64 * 256) {
        float4 v = ((const float4*)src)[i];
        m = fmaxf(m, fmaxf(fmaxf(fabsf(v.x), fabsf(v.y)), fmaxf(fabsf(v.z), fabsf(v.w))));
    }
    #pragma unroll
    for (int mask = 32; mask > 0; mask >>= 1)
        m = fmaxf(m, __shfl_xor(m, mask));
    __shared__ float red[4];
    int w = tid >> 6;
    if ((tid & 63) == 0) red[w] = m;
    __syncthreads();
    if (tid == 0) {
        m = fmaxf(fmaxf(red[0], red[1]), fmaxf(red[2], red[3]));
        atomicMax((int*)(amax + t), __float_as_int(m));
    }
}

// ---------------------------------------------------------------- weight prep (quant + fold)
__global__ __launch_bounds__(256) void prep_w(const float* __restrict__ wq,
                                              const float* __restrict__ wk,
                                              const float* __restrict__ wv,
                                              const float* __restrict__ wo,
                                              const float* __restrict__ wu,
                                              const float* __restrict__ wsv,
                                              const float* __restrict__ amax,
                                              bf16_t* __restrict__ W_all,
                                              bf16_t* __restrict__ Wo) {
    const int which = blockIdx.y;
    if (blockIdx.x < 512) {
        const float* src = which ? wo : wv;
        bf16_t* dst = which ? Wo : (W_all + (size_t)2048 * 1024);
        float s = amax[which ? 3 : 2] / 31.0f + 1e-8f;
        int i = (blockIdx.x * 256 + threadIdx.x) * 8;
        float4 f0 = *(const float4*)(src + i);
        float4 f1 = *(const float4*)(src + i + 4);
        bf16x8 v;
        v[0] = (bf16_t)quant6(f0.x, s); v[1] = (bf16_t)quant6(f0.y, s);
        v[2] = (bf16_t)quant6(f0.z, s); v[3] = (bf16_t)quant6(f0.w, s);
        v[4] = (bf16_t)quant6(f1.x, s); v[5] = (bf16_t)quant6(f1.y, s);
        v[6] = (bf16_t)quant6(f1.z, s); v[7] = (bf16_t)quant6(f1.w, s);
        *(bf16x8*)(dst + i) = v;
        return;
    }
    const int fx = blockIdx.x - 512;
    const float* wbig = which ? wk : wq;
    const float* wsml = which ? wsv : wu;
    const float sb = amax[which ? 1 : 0] / 31.0f + 1e-8f;
    const float ss = amax[which ? 5 : 4] / 31.0f + 1e-8f;
    const float oscale = which ? 1.0f : 0.125f * 1.44269504089f;
    bf16_t* outp = W_all + (size_t)which * 1024 * 1024;
    const int h = fx >> 4, n0 = (fx & 15) * 64;
    const int w = threadIdx.x >> 6, l = threadIdx.x & 63;
    const int l15 = l & 15, quad = l >> 4, q8 = quad * 8;
    const int m0 = w * 16;

    bf16x8 af[2];
    #pragma unroll
    for (int kc = 0; kc < 2; ++kc) {
        const float* src = wsml + (m0 + l15) * 64 + kc * 32 + q8;
        float4 f0 = *(const float4*)(src);
        float4 f1 = *(const float4*)(src + 4);
        bf16x8 a;
        a[0] = (bf16_t)quant6(f0.x, ss); a[1] = (bf16_t)quant6(f0.y, ss);
        a[2] = (bf16_t)quant6(f0.z, ss); a[3] = (bf16_t)quant6(f0.w, ss);
        a[4] = (bf16_t)quant6(f1.x, ss); a[5] = (bf16_t)quant6(f1.y, ss);
        a[6] = (bf16_t)quant6(f1.z, ss); a[7] = (bf16_t)quant6(f1.w, ss);
        af[kc] = a;
    }
    f32x4 acc[4];
    #pragma unroll
    for (int nb = 0; nb < 4; ++nb) acc[nb] = (f32x4){0.f, 0.f, 0.f, 0.f};
    #pragma unroll
    for (int kc = 0; kc < 2; ++kc) {
        #pragma unroll
        for (int nb = 0; nb < 4; ++nb) {
            bf16x8 bfr;
            #pragma unroll
            for (int j = 0; j < 8; ++j)
                bfr[j] = (bf16_t)quant6(wbig[(size_t)(h * 64 + kc * 32 + q8 + j) * 1024 + n0 + nb * 16 + l15], sb);
            acc[nb] = __builtin_amdgcn_mfma_f32_16x16x32_bf16(af[kc], bfr, acc[nb], 0, 0, 0);
        }
    }
    #pragma unroll
    for (int nb = 0; nb < 4; ++nb)
        #pragma unroll
        for (int r = 0; r < 4; ++r)
            outp[(size_t)(h * 64 + m0 + quad * 4 + r) * 1024 + n0 + nb * 16 + l15] =
                (bf16_t)(acc[nb][r] * oscale);
}

// ---------------------------------------------------------------- GEMM  C[M,N] = A[M,K] * Bt[N,K]^T
// Single-buffer 32KB LDS (R14-proven): 4 blocks/CU occupancy beats drain amortization.
// FUSE_VT: V-column tiles (n0 >= 2048) write straight to Vt[bh][s][t] (bf16x4 over the
// 4 consecutive rows held in acc[..][r]) and skip the C store — vtrans eliminated.
template <bool OUT_F32, bool FUSE_VT>
__global__ __launch_bounds__(256) void gemm128(const bf16_t* __restrict__ A,
                                               const bf16_t* __restrict__ Bt,
                                               void* __restrict__ Cv,
                                               bf16_t* __restrict__ Vt,
                                               int lda, int ldb, int ldc, int K) {
    __shared__ __align__(16) bf16_t As[128 * 64];
    __shared__ __align__(16) bf16_t Bs[128 * 64];
    const int tid = threadIdx.x;
    const int w = tid >> 6, l = tid & 63;
    const int l15 = l & 15, quad = l >> 4;
    const int m0 = blockIdx.y * 128, n0 = blockIdx.x * 128;
    const int wm = (w & 1) * 64, wn = (w >> 1) * 64;

    f32x4 acc[4][4];
    #pragma unroll
    for (int a = 0; a < 4; ++a)
        #pragma unroll
        for (int b = 0; b < 4; ++b) acc[a][b] = (f32x4){0.f, 0.f, 0.f, 0.f};

    for (int kc = 0; kc < K; kc += 64) {
        __syncthreads();
        #pragma unroll
        for (int rep = 0; rep < 4; ++rep) {
            int ci = rep * 256 + w * 64 + l;
            int row = ci >> 3, slot = ci & 7;
            int gch = slot ^ ((row ^ (row >> 3)) & 7);
            __builtin_amdgcn_global_load_lds(
                (glb_u32*)(A + (size_t)(m0 + row) * lda + kc + gch * 8),
                (lds_u32*)(As + (rep * 256 + w * 64) * 8), 16, 0, 0);
            __builtin_amdgcn_global_load_lds(
                (glb_u32*)(Bt + (size_t)(n0 + row) * ldb + kc + gch * 8),
                (lds_u32*)(Bs + (rep * 256 + w * 64) * 8), 16, 0, 0);
        }
        __syncthreads();
        #pragma unroll
        for (int kb = 0; kb < 2; ++kb) {
            bf16x8 af[4], bfr[4];
            #pragma unroll
            for (int mb = 0; mb < 4; ++mb) {
                int row = wm + mb * 16 + l15;
                int slot = ((kb << 2) + quad) ^ ((row ^ (row >> 3)) & 7);
                af[mb] = *(const bf16x8*)(As + (row << 6) + slot * 8);
            }
            #pragma unroll
            for (int nb = 0; nb < 4; ++nb) {
                int row = wn + nb * 16 + l15;
                int slot = ((kb << 2) + quad) ^ ((row ^ (row >> 3)) & 7);
                bfr[nb] = *(const bf16x8*)(Bs + (row << 6) + slot * 8);
            }
            #pragma unroll
            for (int mb = 0; mb < 4; ++mb)
                #pragma unroll
                for (int nb = 0; nb < 4; ++nb)
                    acc[mb][nb] = __builtin_amdgcn_mfma_f32_16x16x32_bf16(af[mb], bfr[nb], acc[mb][nb], 0, 0, 0);
        }
    }
    if constexpr (FUSE_VT) {
        if (n0 >= 2048) {
            // V part: row = b*2048 + t, col-2048 = h*64 + s.  acc[mb][nb][r] over r is
            // 4 consecutive t at fixed s -> one bf16x4 store each (8B, 8B-aligned).
            const int b = m0 >> 11;
            const int tb = (m0 & 2047) + wm;
            #pragma unroll
            for (int nb = 0; nb < 4; ++nb) {
                int colv = (n0 - 2048) + wn + nb * 16 + l15;
                int h = colv >> 6, s = colv & 63;
                bf16_t* vrow = Vt + ((size_t)((b * 16 + h) * 64 + s)) * 2048;
                #pragma unroll
                for (int mb = 0; mb < 4; ++mb) {
                    bf16x4 v;
                    #pragma unroll
                    for (int r = 0; r < 4; ++r) v[r] = (bf16_t)acc[mb][nb][r];
                    *(bf16x4*)(vrow + tb + mb * 16 + quad * 4) = v;
                }
            }
            return;
        }
    }
    #pragma unroll
    for (int mb = 0; mb < 4; ++mb) {
        #pragma unroll
        for (int nb = 0; nb < 4; ++nb) {
            int col = n0 + wn + nb * 16 + l15;
            #pragma unroll
            for (int r = 0; r < 4; ++r) {
                int row = m0 + wm + mb * 16 + quad * 4 + r;
                if constexpr (OUT_F32)
                    ((float*)Cv)[(size_t)row * ldc + col] = acc[mb][nb][r];
                else
                    ((bf16_t*)Cv)[(size_t)row * ldc + col] = (bf16_t)acc[mb][nb][r];
            }
        }
    }
}

// ---------------------------------------------------------------- attention (transposed scores)
// Sᵀ = mfma(K, Q): lane holds S[q = l15][kpos = c*16 + quad*4 + r].
// 4 q-tiles per block share each kb/vb fragment read. Two phases per k-tile:
//   phase 1 (kb live): per active tile: bias-init sacc, QK MFMA, exp2, P -> LDS.
//   phase 2 (vb live): per active tile: read P fragment, PV MFMA + ones row-sum.
// 16B-block swizzle on K/V/P keeps banks <=2-way.
__global__ __launch_bounds__(256, 2) void attn_kernel(const bf16_t* __restrict__ QKV,
                                                      const bf16_t* __restrict__ Vt,
                                                      const float* __restrict__ Bias,
                                                      bf16_t* __restrict__ O) {
    __shared__ __align__(16) bf16_t Ks[2 * 64 * 64];
    __shared__ __align__(16) bf16_t Vs[2 * 64 * 64];
    __shared__ __align__(16) bf16_t Ps[4 * 4 * 16 * 64];   // [wave][tile][16 q][64 k]

    const int tid = threadIdx.x;
    const int w = tid >> 6, l = tid & 63;
    const int l15 = l & 15, quad = l >> 4, q8 = quad * 8;
    const int p = (blockIdx.x >> 3) & 7;
    const int bh = (blockIdx.x & 7) + ((blockIdx.x >> 6) << 3);
    const int b = bh >> 4, h = bh & 15;
    const int qt[4] = {p, 15 - p, 16 + p, 31 - p};

    const size_t xbase = (size_t)b * TT * 3072;

    bf16x8 qa[4][2];
    #pragma unroll
    for (int t = 0; t < 4; ++t)
        #pragma unroll
        for (int kc = 0; kc < 2; ++kc)
            qa[t][kc] = *(const bf16x8*)(QKV + xbase + (size_t)(qt[t] * 64 + w * 16 + l15) * 3072 + h * 64 + kc * 32 + q8);

    bf16x8 ones;
    #pragma unroll
    for (int j = 0; j < 8; ++j) ones[j] = (bf16_t)1.0f;

    f32x4 oacc[4][4], lacc[4];
    #pragma unroll
    for (int t = 0; t < 4; ++t) {
        lacc[t] = (f32x4){0.f, 0.f, 0.f, 0.f};
        #pragma unroll
        for (int i = 0; i < 4; ++i) oacc[t][i] = (f32x4){0.f, 0.f, 0.f, 0.f};
    }
    bf16_t* Pw = Ps + w * 4096;

    // stage k-tile kt into LDS half hb (4 x global_load_lds per wave, 16B each)
    auto STAGE = [&](int kt, int hb) {
        #pragma unroll
        for (int rep = 0; rep < 2; ++rep) {
            int ci = rep * 256 + tid;
            int row = ci >> 3, slot = ci & 7;
            int gch = slot ^ ((row ^ (row >> 3)) & 7);
            __builtin_amdgcn_global_load_lds(
                (glb_u32*)(QKV + xbase + (size_t)(kt * 64 + row) * 3072 + 1024 + h * 64 + gch * 8),
                (lds_u32*)(Ks + hb * 4096 + (rep * 256 + w * 64) * 8), 16, 0, 0);
            __builtin_amdgcn_global_load_lds(
                (glb_u32*)(Vt + (size_t)bh * 131072 + (size_t)row * 2048 + kt * 64 + gch * 8),
                (lds_u32*)(Vs + hb * 4096 + (rep * 256 + w * 64) * 8), 16, 0, 0);
        }
    };

    // compute all 4 q-tiles for k-tile kt from LDS half hb
    auto COMPUTE = [&](int kt, int hb) {
        // ---- phase 1: K fragments live; QK + softmax + P store per active tile
        {
            bf16x8 kb[4][2];
            #pragma unroll
            for (int kc = 0; kc < 2; ++kc)
                #pragma unroll
                for (int c = 0; c < 4; ++c) {
                    int row = c * 16 + l15;
                    int slot = (kc * 4 + quad) ^ ((row ^ (row >> 3)) & 7);
                    kb[c][kc] = *(const bf16x8*)(Ks + hb * 4096 + row * 64 + slot * 8);
                }
            #pragma unroll
            for (int t = 0; t < 4; ++t) {
                if (kt > qt[t]) continue;   // wave-uniform
                const float* bp = Bias + ((((size_t)(qt[t] - kt) * 4 + w) * 4) * 64 + l) * 4;
                f32x4 sacc[4];
                #pragma unroll
                for (int c = 0; c < 4; ++c) sacc[c] = *(const f32x4*)(bp + c * 256);
                #pragma unroll
                for (int kc = 0; kc < 2; ++kc)
                    #pragma unroll
                    for (int c = 0; c < 4; ++c)
                        sacc[c] = __builtin_amdgcn_mfma_f32_16x16x32_bf16(kb[c][kc], qa[t][kc], sacc[c], 0, 0, 0);
                #pragma unroll
                for (int c = 0; c < 4; ++c) {
                    bf16x4 pk;
                    #pragma unroll
                    for (int r = 0; r < 4; ++r)
                        pk[r] = (bf16_t)fexp2(sacc[c][r]);   // -inf (masked) -> 0
                    int pp = (c * 2 + (quad >> 1)) ^ (l15 & 7);
                    *(bf16x4*)(Pw + t * 1024 + l15 * 64 + pp * 8 + (quad & 1) * 4) = pk;
                }
            }
        }
        __builtin_amdgcn_wave_barrier();
        // ---- phase 2: V fragments live; PV + ones row-sum per active tile
        {
            bf16x8 vb[4][2];
            #pragma unroll
            for (int kc = 0; kc < 2; ++kc)
                #pragma unroll
                for (int c = 0; c < 4; ++c) {
                    int row = c * 16 + l15;
                    int slot = (kc * 4 + quad) ^ ((row ^ (row >> 3)) & 7);
                    vb[c][kc] = *(const bf16x8*)(Vs + hb * 4096 + row * 64 + slot * 8);
                }
            #pragma unroll
            for (int t = 0; t < 4; ++t) {
                if (kt > qt[t]) continue;
                #pragma unroll
                for (int kc = 0; kc < 2; ++kc) {
                    bf16x8 pa = *(const bf16x8*)(Pw + t * 1024 + l15 * 64 + (((kc * 4 + quad) ^ (l15 & 7)) * 8));
                    #pragma unroll
                    for (int sb = 0; sb < 4; ++sb)
                        oacc[t][sb] = __builtin_amdgcn_mfma_f32_16x16x32_bf16(pa, vb[sb][kc], oacc[t][sb], 0, 0, 0);
                    lacc[t] = __builtin_amdgcn_mfma_f32_16x16x32_bf16(pa, ones, lacc[t], 0, 0, 0);
                }
            }
        }
        __builtin_amdgcn_wave_barrier();
    };

    const int nkt = qt[3] + 1;   // 32 - p
    for (int kt2 = 0; kt2 < nkt; kt2 += 2) {
        const bool has2 = (kt2 + 1) < nkt;
        // Barrier 1: all waves finished reading both halves of the previous pair.
        __syncthreads();
        STAGE(kt2, 0);
        if (has2) STAGE(kt2 + 1, 1);
        // Barrier 2: one vmcnt drain covers BOTH tiles' loads (they pipeline).
        __syncthreads();
        COMPUTE(kt2, 0);
        if (has2) COMPUTE(kt2 + 1, 1);
    }

    // epilogue: lacc[t][r] holds the full denominator for row q = quad*4+r of tile t.
    #pragma unroll
    for (int t = 0; t < 4; ++t) {
        #pragma unroll
        for (int r = 0; r < 4; ++r) {
            float invr = 1.0f / lacc[t][r];
            #pragma unroll
            for (int sb = 0; sb < 4; ++sb) {
                int q = qt[t] * 64 + w * 16 + quad * 4 + r;
                int col = h * 64 + sb * 16 + l15;
                O[(size_t)(b * TT + q) * DD + col] = (bf16_t)(oacc[t][sb][r] * invr);
            }
        }
    }
}

// ---------------------------------------------------------------- launch
extern "C" void kernel_launch(void* const* d_in, const int* in_sizes, int n_in,
                              void* d_out, int out_size, void* d_ws, size_t ws_size,
                              hipStream_t stream) {
    const float* x   = (const float*)d_in[0];
    const float* wq  = (const float*)d_in[1];
    const float* wk  = (const float*)d_in[2];
    const float* wv  = (const float*)d_in[3];
    const float* wo  = (const float*)d_in[4];
    const float* wu  = (const float*)d_in[5];
    const float* wsv = (const float*)d_in[6];
    const float* psc = (const float*)d_in[7];
    float* out = (float*)d_out;

    char* ws = (char*)d_ws;
    float*  amax  = (float*)(ws);
    bf16_t* W_all = (bf16_t*)(ws + 256);                       // 3072x1024 bf16 (6291456 B)
    bf16_t* Wo    = (bf16_t*)(ws + 6291712);                   // 1024x1024 bf16 (2097152 B)
    bf16_t* xb    = (bf16_t*)(ws + 8388864);                   // 8192x1024 bf16 (16777216 B)
    bf16_t* Obuf  = xb;                                        // reuse: xb dead after GEMM1
    bf16_t* QKV   = (bf16_t*)(ws + 25166080);                  // 8192x3072 bf16 (50331648 B)
    bf16_t* Vt    = (bf16_t*)(ws + 75497728);                  // 64bh x 64s x 2048t bf16 (16777216 B)
    float*  Bias  = (float*)(ws + 92274944);                   // 128 x 1024 f32 (524288 B)

    // fused prologue: xcvt + ptable + absmax6 (one launch)
    hipLaunchKernelGGL(pre_kernel, dim3(4608), dim3(256), 0, stream,
                       x, xb, psc, Bias, wq, wk, wv, wo, wu, wsv, amax);
    hipLaunchKernelGGL(prep_w, dim3(768, 2), dim3(256), 0, stream,
                       wq, wk, wv, wo, wu, wsv, amax, W_all, Wo);

    // GEMM1: QKV = xb @ W_all^T   (M=8192, N=3072, K=1024); V tiles write Vt directly
    hipLaunchKernelGGL((gemm128<false, true>), dim3(24, 64), dim3(256), 0, stream,
                       xb, W_all, (void*)QKV, Vt, 1024, 1024, 3072, 1024);

    // attention (512 blocks: bh x 8 tile-quads, XCD-swizzled; exactly 2 blocks/CU)
    hipLaunchKernelGGL(attn_kernel, dim3(512), dim3(256), 0, stream, QKV, Vt, Bias, Obuf);

    // GEMM2: out = O @ Wo^T   (M=8192, N=1024, K=1024)
    hipLaunchKernelGGL((gemm128<true, false>), dim3(8, 64), dim3(256), 0, stream,
                       Obuf, Wo, (void*)out, nullptr, 1024, 1024, 1024, 1024);
}